// Round 13
// baseline (888.611 us; speedup 1.0000x reference)
//
#include <hip/hip_runtime.h>
#include <math.h>

// ---------------- constants ----------------
#define S_ 2
#define B_ 8
#define N_ 12
#define A_ 4
#define L_ 24
#define C_ 256
#define AUX_ 16
#define EK_ 64
#define K_ 256
#define M_ 8
#define OTH_ 32
#define D2_ 272
#define FF_ 2048
#define RIN_ 736
#define NSTR_ (S_*B_*N_*A_)   // 768
#define NCVT_ 256             // cvt chunks in the work queue
#define T4_ (5441536/4)       // 1360384 float4 chunks of weight data
#define CSZ_ (T4_/NCVT_)      // 5314 float4 per chunk (exact)

typedef __attribute__((ext_vector_type(8))) short short8v;   // bf16x8 MFMA frag
typedef __attribute__((ext_vector_type(4))) float f32x4;     // MFMA acc

__device__ __forceinline__ unsigned short f2bf(float f) {     // RNE f32->bf16
    unsigned u = __float_as_uint(f);
    return (unsigned short)((u + 0x7FFFu + ((u >> 16) & 1u)) >> 16);
}

// ---------------- K0: renorm char table (max_norm=1) ----------------
__global__ void scale_table_k(const float* __restrict__ tbl, float* __restrict__ out) {
    int r = blockIdx.x;          // 128 rows
    int c = threadIdx.x;         // 256
    float v = tbl[r * C_ + c];
    float sq = v * v;
    for (int off = 32; off; off >>= 1) sq += __shfl_down(sq, off);
    __shared__ float red[4];
    __shared__ float scl;
    if ((c & 63) == 0) red[c >> 6] = sq;
    __syncthreads();
    if (c == 0) {
        float n = sqrtf(red[0] + red[1] + red[2] + red[3]);
        scl = fminf(1.f, 1.f / fmaxf(n, 1e-7f));
    }
    __syncthreads();
    out[r * C_ + c] = v * scl;
}

// ---- K1: work-queue kernel: 768 strings + 256 weight-cvt chunks -----------
__global__ void attvec_k(const int* __restrict__ chars, const int* __restrict__ att_type,
                         const int* __restrict__ kw_idx, const float* __restrict__ tblS,
                         const float* __restrict__ fw, const float* __restrict__ fb,
                         const float* __restrict__ gw, const float* __restrict__ gb,
                         const float* __restrict__ mw, const float* __restrict__ mb,
                         const float* __restrict__ kwt, const float* __restrict__ aw,
                         const float* __restrict__ ab, float* __restrict__ x1,
                         unsigned short* __restrict__ x1b, int* __restrict__ ctr,
                         const float* __restrict__ s0, const float* __restrict__ s1,
                         const float* __restrict__ s2, const float* __restrict__ s3,
                         const float* __restrict__ s4, const float* __restrict__ s5,
                         unsigned short* __restrict__ wdst) {
    int tid = threadIdx.x;       // 0..1023
    int grp = tid >> 8;          // 0..3
    int c = tid & 255;
    __shared__ int su;
    __shared__ int ch[L_];
    __shared__ float xv[L_ + 2][C_];
    __shared__ float part[4][C_];

    const float L2E = 1.44269504f;
    float f0[4], f1[4], f2[4], fbv[4], g0[4], g1[4], g2[4], gbv[4], mwv[4];
    #pragma unroll
    for (int oo = 0; oo < 4; ++oo) {
        int o = grp * 4 + oo;
        f0[oo] = 2.f*L2E*fw[o*3]; f1[oo] = 2.f*L2E*fw[o*3+1]; f2[oo] = 2.f*L2E*fw[o*3+2];
        fbv[oo] = 2.f*L2E*fb[o];
        g0[oo] = L2E*gw[o*3]; g1[oo] = L2E*gw[o*3+1]; g2[oo] = L2E*gw[o*3+2];
        gbv[oo] = L2E*gb[o];
        mwv[oo] = mw[o];
    }

    for (;;) {
        __syncthreads();
        if (tid == 0) su = atomicAdd(ctr, 1);
        __syncthreads();
        int item = su;
        if (item >= NSTR_ + NCVT_) break;

        if (item >= NSTR_) {                     // ---- weight-cvt chunk ----
            int base = (item - NSTR_) * CSZ_;
            #pragma unroll
            for (int i = 0; i < 6; ++i) {
                int q = base + i * 1024 + tid;
                if (q < base + CSZ_) {
                    int idx = q * 4;
                    const float* src; int off;
                    if      (idx < 524288)  { src = s0; off = 0; }
                    else if (idx < 1572864) { src = s1; off = 524288; }
                    else if (idx < 2621440) { src = s2; off = 1572864; }
                    else if (idx < 3213312) { src = s3; off = 2621440; }
                    else if (idx < 4327424) { src = s4; off = 3213312; }
                    else                    { src = s5; off = 4327424; }
                    float4 v = *(const float4*)(src + (idx - off));
                    ushort4 o;
                    o.x = f2bf(v.x); o.y = f2bf(v.y); o.z = f2bf(v.z); o.w = f2bf(v.w);
                    *(ushort4*)(wdst + idx) = o;
                }
            }
            continue;
        }

        int str = item;
        bool kw = (att_type[str] == 1);
        float partial;
        if (kw) {
            const float* kr = kwt + kw_idx[str] * EK_ + grp * 16;
            const float* awr = aw + c * EK_ + grp * 16;
            float acc = (grp == 0) ? ab[c] : 0.f;
            #pragma unroll
            for (int e = 0; e < 16; ++e) acc = fmaf(kr[e], awr[e], acc);
            partial = acc;
        } else {
            if (tid < L_) ch[tid] = chars[str * L_ + tid];
            __syncthreads();
            #pragma unroll
            for (int i = 0; i < 6; ++i) {
                int l = grp * 6 + i;
                xv[l + 1][c] = tblS[ch[l] * C_ + c];
            }
            if (grp == 0) xv[0][c] = 0.f;
            if (grp == 3) xv[L_ + 1][c] = 0.f;
            __syncthreads();

            float osum[4] = {0.f, 0.f, 0.f, 0.f};
            float xm = xv[0][c], x0 = xv[1][c];
            for (int l = 1; l <= L_; ++l) {
                float xp = xv[l + 1][c];
                #pragma unroll
                for (int oo = 0; oo < 4; ++oo) {
                    float pf2 = fbv[oo] + f0[oo]*xm + f1[oo]*x0 + f2[oo]*xp;
                    float pg  = gbv[oo] + g0[oo]*xm + g1[oo]*x0 + g2[oo]*xp;
                    pf2 = fminf(fmaxf(pf2, -43.f), 43.f);
                    pg  = fminf(fmaxf(pg,  -22.f), 22.f);
                    float e1 = __builtin_amdgcn_exp2f(pf2);
                    float e2 = __builtin_amdgcn_exp2f(pg);
                    float num = (e1 - 1.f) * e2;
                    float den = (e1 + 1.f) * (e2 + 1.f);
                    osum[oo] = fmaf(num, __builtin_amdgcn_rcpf(den), osum[oo]);
                }
                xm = x0; x0 = xp;
            }
            partial = mwv[0]*osum[0] + mwv[1]*osum[1] + mwv[2]*osum[2] + mwv[3]*osum[3];
        }
        part[grp][c] = partial;
        __syncthreads();
        if (grp == 0) {
            int a = str & 3;
            int n = (str >> 2) % N_;
            int sb = str / (N_ * A_);
            int row = n * 64 + sb * 4 + a;
            float tot = part[0][c] + part[1][c] + part[2][c] + part[3][c];
            float out = kw ? tot : (mb[0] + tot * (1.f / 24.f));
            x1[row * C_ + c] = out;
            x1b[row * C_ + c] = f2bf(out);
        }
    }
}

// ---------------- MFMA GEMM, 2-deep register prefetch ----------------------
// gridDim.z == 1: direct out (f32 or bf16 via obf, +bias+relu).
// gridDim.z > 1 : f32 partials to Cf + z*R*N, no bias.
__global__ void gemm_mfma_k(const unsigned short* __restrict__ Ab,
                            const unsigned short* __restrict__ Wb,
                            const float* __restrict__ bias,
                            float* __restrict__ Cf, unsigned short* __restrict__ Cb,
                            int R, int K, int N, int relu, int kslice, int obf) {
    int tid = threadIdx.x;
    int wave = tid >> 6, lane = tid & 63;
    int fr = lane & 15, fq = lane >> 4;
    int m0 = blockIdx.y * 64;
    int n0 = blockIdx.x * 64 + wave * 16;
    int kbeg = blockIdx.z * kslice;
    int kend = min(kbeg + kslice, K);
    int col = n0 + fr;
    bool bok = col < N;
    const unsigned short* Wrow = Wb + (size_t)col * K;
    const unsigned short* Ar0 = Ab + (size_t)(m0 + fr) * K;
    const unsigned short* Ar1 = Ab + (size_t)(m0 + 16 + fr) * K;
    const unsigned short* Ar2 = Ab + (size_t)(m0 + 32 + fr) * K;
    const unsigned short* Ar3 = Ab + (size_t)(m0 + 48 + fr) * K;

    f32x4 acc0 = {0.f,0.f,0.f,0.f}, acc1 = {0.f,0.f,0.f,0.f};
    f32x4 acc2 = {0.f,0.f,0.f,0.f}, acc3 = {0.f,0.f,0.f,0.f};
    const short8v z8 = {0,0,0,0,0,0,0,0};
    short8v pb0, pa00, pa01, pa02, pa03;
    short8v pb1, pa10, pa11, pa12, pa13;

#define LDSET(PB,PA0,PA1,PA2,PA3,ktv) do {                                \
        int kl2 = (ktv) + fq * 8;                                         \
        bool kv2 = (kl2 + 8 <= kend);                                     \
        PB  = (bok && kv2) ? *(const short8v*)(Wrow + kl2) : z8;          \
        PA0 = kv2 ? *(const short8v*)(Ar0 + kl2) : z8;                    \
        PA1 = kv2 ? *(const short8v*)(Ar1 + kl2) : z8;                    \
        PA2 = kv2 ? *(const short8v*)(Ar2 + kl2) : z8;                    \
        PA3 = kv2 ? *(const short8v*)(Ar3 + kl2) : z8;                    \
    } while (0)

    if (kbeg < kend) {
        LDSET(pb0, pa00, pa01, pa02, pa03, kbeg);
        LDSET(pb1, pa10, pa11, pa12, pa13, kbeg + 32);
        for (int kt = kbeg; kt < kend; kt += 64) {
            short8v tb = pb0, t0 = pa00, t1 = pa01, t2 = pa02, t3 = pa03;
            LDSET(pb0, pa00, pa01, pa02, pa03, kt + 64);
            acc0 = __builtin_amdgcn_mfma_f32_16x16x32_bf16(t0, tb, acc0, 0, 0, 0);
            acc1 = __builtin_amdgcn_mfma_f32_16x16x32_bf16(t1, tb, acc1, 0, 0, 0);
            acc2 = __builtin_amdgcn_mfma_f32_16x16x32_bf16(t2, tb, acc2, 0, 0, 0);
            acc3 = __builtin_amdgcn_mfma_f32_16x16x32_bf16(t3, tb, acc3, 0, 0, 0);
            short8v ub = pb1, u0 = pa10, u1 = pa11, u2 = pa12, u3 = pa13;
            LDSET(pb1, pa10, pa11, pa12, pa13, kt + 96);
            acc0 = __builtin_amdgcn_mfma_f32_16x16x32_bf16(u0, ub, acc0, 0, 0, 0);
            acc1 = __builtin_amdgcn_mfma_f32_16x16x32_bf16(u1, ub, acc1, 0, 0, 0);
            acc2 = __builtin_amdgcn_mfma_f32_16x16x32_bf16(u2, ub, acc2, 0, 0, 0);
            acc3 = __builtin_amdgcn_mfma_f32_16x16x32_bf16(u3, ub, acc3, 0, 0, 0);
        }
    }
#undef LDSET

    if (!bok) return;
    bool direct = (gridDim.z == 1);
    float bv = direct ? bias[col] : 0.f;
    float* outf = direct ? Cf : (Cf + (size_t)blockIdx.z * R * N);
#define STOREACC(accv, mi) do {                                           \
        _Pragma("unroll")                                                 \
        for (int j = 0; j < 4; ++j) {                                     \
            int row = m0 + (mi)*16 + fq * 4 + j;                          \
            float v = accv[j] + bv;                                       \
            if (direct && relu) v = fmaxf(v, 0.f);                        \
            if (direct && obf) Cb[(size_t)row * N + col] = f2bf(v);       \
            else               outf[(size_t)row * N + col] = v;           \
        }                                                                 \
    } while (0)
    STOREACC(acc0, 0); STOREACC(acc1, 1); STOREACC(acc2, 2); STOREACC(acc3, 3);
#undef STOREACC
}

// ======= GEMM with LN-PROLOGUE: A = LN(xres + bias_p + sum_z partials) =====
// Each block computes LN for its own 64 A-rows into an LDS bf16 tile (no
// cross-block communication; redundant across n-blocks, deterministic).
// blockIdx.x==0 blocks also write the f32 LN result to x_out (ping-pong:
// x_out != xres, so no intra-dispatch race). Then C = A @ W^T + bias.
__global__ void gemm_pro_k(const float* __restrict__ part, int NS,
                           const float* __restrict__ xres,
                           const float* __restrict__ bias_p,
                           const float* __restrict__ lng, const float* __restrict__ lnb,
                           float* __restrict__ x_out,
                           const unsigned short* __restrict__ Wb,
                           const float* __restrict__ bias,
                           float* __restrict__ Cf, unsigned short* __restrict__ Cb,
                           int R, int K, int N, int relu, int obf) {
    __shared__ unsigned short lnA[64][280];    // K<=272, stride 280 (16B rows)
    int tid = threadIdx.x;                     // 256
    int wave = tid >> 6, lane = tid & 63;
    int fr = lane & 15, fq = lane >> 4;
    int m0 = blockIdx.y * 64;
    int n0 = blockIdx.x * 64 + wave * 16;
    const short8v z8 = {0,0,0,0,0,0,0,0};

    // ---- LN prologue: wave w handles rows m0+w*16 .. +15 ----
    for (int i = 0; i < 16; ++i) {
        int r = m0 + wave * 16 + i;
        size_t g = (size_t)r * K;
        float v[5];
        float s = 0.f, ss = 0.f;
        #pragma unroll
        for (int q = 0; q < 5; ++q) {
            int cc = lane + q * 64;
            float val = 0.f;
            if (cc < K) {
                val = xres[g + cc] + bias_p[cc];
                for (int z = 0; z < NS; ++z)
                    val += part[(size_t)z * R * K + g + cc];
            }
            v[q] = val; s += val; ss += val * val;
        }
        #pragma unroll
        for (int off = 32; off; off >>= 1) {
            s += __shfl_xor(s, off);
            ss += __shfl_xor(ss, off);
        }
        float mu = s / K;
        float inv = rsqrtf(ss / K - mu * mu + 1e-5f);
        #pragma unroll
        for (int q = 0; q < 5; ++q) {
            int cc = lane + q * 64;
            if (cc < K) {
                float o = (v[q] - mu) * inv * lng[cc] + lnb[cc];
                lnA[wave * 16 + i][cc] = f2bf(o);
                if (blockIdx.x == 0) x_out[g + cc] = o;
            }
        }
    }
    __syncthreads();

    // ---- GEMM: A from LDS, W from global ----
    int col = n0 + fr;
    bool bok = col < N;
    const unsigned short* Wrow = Wb + (size_t)col * K;
    f32x4 acc0 = {0.f,0.f,0.f,0.f}, acc1 = {0.f,0.f,0.f,0.f};
    f32x4 acc2 = {0.f,0.f,0.f,0.f}, acc3 = {0.f,0.f,0.f,0.f};
    for (int kt = 0; kt < K; kt += 32) {
        int kl = kt + fq * 8;
        bool kv = (kl + 8 <= K);
        short8v bf  = (bok && kv) ? *(const short8v*)(Wrow + kl) : z8;
        short8v af0 = kv ? *(const short8v*)(&lnA[fr][kl])      : z8;
        short8v af1 = kv ? *(const short8v*)(&lnA[16 + fr][kl]) : z8;
        short8v af2 = kv ? *(const short8v*)(&lnA[32 + fr][kl]) : z8;
        short8v af3 = kv ? *(const short8v*)(&lnA[48 + fr][kl]) : z8;
        acc0 = __builtin_amdgcn_mfma_f32_16x16x32_bf16(af0, bf, acc0, 0, 0, 0);
        acc1 = __builtin_amdgcn_mfma_f32_16x16x32_bf16(af1, bf, acc1, 0, 0, 0);
        acc2 = __builtin_amdgcn_mfma_f32_16x16x32_bf16(af2, bf, acc2, 0, 0, 0);
        acc3 = __builtin_amdgcn_mfma_f32_16x16x32_bf16(af3, bf, acc3, 0, 0, 0);
    }

    if (!bok) return;
    float bv = bias[col];
#define STOREACC(accv, mi) do {                                           \
        _Pragma("unroll")                                                 \
        for (int j = 0; j < 4; ++j) {                                     \
            int row = m0 + (mi)*16 + fq * 4 + j;                          \
            float v = accv[j] + bv;                                       \
            if (relu) v = fmaxf(v, 0.f);                                  \
            if (obf) Cb[(size_t)row * N + col] = f2bf(v);                 \
            else     Cf[(size_t)row * N + col] = v;                       \
        }                                                                 \
    } while (0)
    STOREACC(acc0, 0); STOREACC(acc1, 1); STOREACC(acc2, 2); STOREACC(acc3, 3);
#undef STOREACC
}

// ------- fused split-K reduce + bias + residual + LayerNorm (in place) -----
__global__ void redln_k(const float* __restrict__ part, const float* __restrict__ bias,
                        float* __restrict__ x, unsigned short* __restrict__ xb,
                        const float* __restrict__ g, const float* __restrict__ b,
                        int d, int NS, int RN) {
    int r = blockIdx.x, tid = threadIdx.x;
    __shared__ float red[10];
    const float* xr = x + (size_t)r * d;
    int i0 = tid, i1 = tid + 256;
    bool h0 = i0 < d, h1 = i1 < d;
    float v0 = 0.f, v1 = 0.f;
    if (h0) {
        v0 = xr[i0] + bias[i0];
        for (int z = 0; z < NS; ++z) v0 += part[(size_t)z * RN + (size_t)r * d + i0];
    }
    if (h1) {
        v1 = xr[i1] + bias[i1];
        for (int z = 0; z < NS; ++z) v1 += part[(size_t)z * RN + (size_t)r * d + i1];
    }
    float s = v0 + v1, ss = v0 * v0 + v1 * v1;
    for (int off = 32; off; off >>= 1) {
        s += __shfl_down(s, off);
        ss += __shfl_down(ss, off);
    }
    if ((tid & 63) == 0) { red[(tid >> 6) * 2] = s; red[(tid >> 6) * 2 + 1] = ss; }
    __syncthreads();
    if (tid == 0) {
        float S = red[0] + red[2] + red[4] + red[6];
        float SS = red[1] + red[3] + red[5] + red[7];
        float mu = S / d;
        float var = SS / d - mu * mu;
        red[8] = mu;
        red[9] = rsqrtf(var + 1e-5f);
    }
    __syncthreads();
    float mu = red[8], inv = red[9];
    float* xw = x + (size_t)r * d;
    if (h0) {
        float o = (v0 - mu) * inv * g[i0] + b[i0];
        xw[i0] = o; xb[(size_t)r * d + i0] = f2bf(o);
    }
    if (h1) {
        float o = (v1 - mu) * inv * g[i1] + b[i1];
        xw[i1] = o; xb[(size_t)r * d + i1] = f2bf(o);
    }
}

// ---------------- attention: 4-lane score dot, padded LDS ------------------
__global__ void attn_k(const float* __restrict__ qkv, unsigned short* __restrict__ ob,
                       int seq, int batch, int d, float scale) {
    __shared__ float sm[3 * 12 * 260];
    __shared__ float sc[12 * 12];
    int j = blockIdx.x, tid = threadIdx.x;
    int dp = d + 4;
    int s3 = 3 * d;
    float* qs = sm;
    float* ks = sm + 12 * 260;
    float* vs = sm + 2 * 12 * 260;
    for (int idx = tid; idx < seq * d; idx += 256) {
        int s = idx / d, cc = idx - s * d;
        const float* base = qkv + (size_t)(s * batch + j) * s3 + cc;
        qs[s * dp + cc] = base[0];
        ks[s * dp + cc] = base[d];
        vs[s * dp + cc] = base[2 * d];
    }
    __syncthreads();
    for (int p4 = tid; p4 < seq * seq * 4; p4 += 256) {
        int p = p4 >> 2, sub = p4 & 3;
        int s = p / seq, t = p - s * seq;
        const float* qp = qs + s * dp;
        const float* kp = ks + t * dp;
        float acc = 0.f;
        for (int cc = sub; cc < d; cc += 4) acc = fmaf(qp[cc], kp[cc], acc);
        acc += __shfl_xor(acc, 1);
        acc += __shfl_xor(acc, 2);
        if (sub == 0) sc[p] = acc * scale;
    }
    __syncthreads();
    if (tid < seq) {
        float m = -1e30f;
        for (int t = 0; t < seq; ++t) m = fmaxf(m, sc[tid * seq + t]);
        float ssum = 0.f;
        for (int t = 0; t < seq; ++t) {
            float e = __expf(sc[tid * seq + t] - m);
            sc[tid * seq + t] = e;
            ssum += e;
        }
        float inv = 1.f / ssum;
        for (int t = 0; t < seq; ++t) sc[tid * seq + t] *= inv;
    }
    __syncthreads();
    for (int c = tid; c < d; c += 256) {
        for (int s = 0; s < seq; ++s) {
            float acc = 0.f;
            for (int t = 0; t < seq; ++t) acc = fmaf(sc[s * seq + t], vs[t * dp + c], acc);
            ob[(size_t)(s * batch + j) * d + c] = f2bf(acc);
        }
    }
}

// ---------------- build x2: mean over attrs + concat static ----------------
__global__ void build_x2_k(const float* __restrict__ y1, const float* __restrict__ stat,
                           float* __restrict__ x2, unsigned short* __restrict__ x2b) {
    int id = blockIdx.x;                 // 192 blocks
    int n = id % N_;
    int b = (id / N_) % B_;
    int s = id / (N_ * B_);
    int orow = b * (S_ * N_) + s * N_ + n;
    for (int c = threadIdx.x; c < D2_; c += 256) {
        float v;
        if (c < C_) {
            int j0 = (s * B_ + b) * A_;
            float acc = 0.f;
            for (int a = 0; a < A_; ++a) acc += y1[(size_t)(n * 64 + j0 + a) * C_ + c];
            v = acc * 0.25f;
        } else {
            v = stat[((size_t)(s * B_ + b) * N_ + n) * AUX_ + (c - C_)];
        }
        x2[(size_t)orow * D2_ + c] = v;
        x2b[(size_t)orow * D2_ + c] = f2bf(v);
    }
}

// ------- regressor (fused node-mean): build real + feats + 2-layer MLP -----
__global__ void regressor_k(const float* __restrict__ y2, const int* __restrict__ input_idx,
                            const float* __restrict__ kwt, const float* __restrict__ other,
                            const float* __restrict__ w1, const float* __restrict__ b1,
                            const float* __restrict__ w2, const float* __restrict__ b2,
                            float* __restrict__ out) {
    int b = blockIdx.x;                  // 8
    int tid = threadIdx.x;               // 256
    __shared__ float realsh[2][D2_];
    __shared__ float feats[RIN_];
    __shared__ float hh[32];
    for (int idx = tid; idx < 2 * D2_; idx += 256) {
        int s = idx / D2_, c = idx - s * D2_;
        float acc = 0.f;
        for (int n = 0; n < N_; ++n)
            acc += y2[(size_t)(b * 24 + s * N_ + n) * D2_ + c];
        realsh[s][c] = acc * (1.f / 12.f);
    }
    __syncthreads();
    for (int i = tid; i < RIN_; i += 256) {
        float v;
        if (i < 64) {
            float acc = 0.f;
            for (int m = 0; m < M_; ++m) acc += kwt[input_idx[b * M_ + m] * EK_ + i];
            v = acc * 0.125f;
        } else if (i < 336) {
            v = realsh[0][i - 64];
        } else if (i < 400) {
            int e = i - 336;
            float acc = 0.f;
            for (int m = 0; m < M_; ++m) acc += kwt[input_idx[64 + b * M_ + m] * EK_ + e];
            v = acc * 0.125f;
        } else if (i < 672) {
            v = realsh[1][i - 400];
        } else {
            v = other[b * 64 + (i - 672)];
        }
        feats[i] = v;
    }
    __syncthreads();
    if (tid < 32) {
        float acc = b1[tid];
        const float* wr = w1 + (size_t)tid * RIN_;
        for (int i = 0; i < RIN_; ++i) acc += feats[i] * wr[i];
        hh[tid] = fmaxf(acc, 0.f);
    }
    __syncthreads();
    if (tid == 0) {
        float acc = b2[0];
        for (int j = 0; j < 32; ++j) acc += hh[j] * w2[j];
        out[b] = acc;
    }
}

// ---------------- host ----------------
extern "C" void kernel_launch(void* const* d_in, const int* in_sizes, int n_in,
                              void* d_out, int out_size, void* d_ws, size_t ws_size,
                              hipStream_t stream) {
    const int*   chars      = (const int*)d_in[0];
    const int*   att_type   = (const int*)d_in[1];
    const int*   kw_idx     = (const int*)d_in[2];
    const int*   input_idx  = (const int*)d_in[3];
    const float* stat       = (const float*)d_in[4];
    const float* other      = (const float*)d_in[5];
    const float* char_table = (const float*)d_in[6];
    const float* filter_w   = (const float*)d_in[7];
    const float* filter_b   = (const float*)d_in[8];
    const float* gate_w     = (const float*)d_in[9];
    const float* gate_b     = (const float*)d_in[10];
    const float* mlp_w      = (const float*)d_in[11];
    const float* mlp_b      = (const float*)d_in[12];
    const float* kw_table   = (const float*)d_in[13];
    const float* aline_w    = (const float*)d_in[14];
    const float* aline_b    = (const float*)d_in[15];
    const float* t1_attn_w  = (const float*)d_in[16];
    const float* t1_attn_b  = (const float*)d_in[17];
    const float* t1_ffn_w1  = (const float*)d_in[18];
    const float* t1_ffn_b1  = (const float*)d_in[19];
    const float* t1_ffn_w2  = (const float*)d_in[20];
    const float* t1_ffn_b2  = (const float*)d_in[21];
    const float* t1_ln_g    = (const float*)d_in[22];
    const float* t1_ln_b    = (const float*)d_in[23];
    const float* t2_attn_w  = (const float*)d_in[24];
    const float* t2_attn_b  = (const float*)d_in[25];
    const float* t2_ffn_w1  = (const float*)d_in[26];
    const float* t2_ffn_b1  = (const float*)d_in[27];
    const float* t2_ffn_w2  = (const float*)d_in[28];
    const float* t2_ffn_b2  = (const float*)d_in[29];
    const float* t2_ln_g    = (const float*)d_in[30];
    const float* t2_ln_b    = (const float*)d_in[31];
    const float* reg_w1     = (const float*)d_in[32];
    const float* reg_b1     = (const float*)d_in[33];
    const float* reg_w2     = (const float*)d_in[34];
    const float* reg_b2     = (const float*)d_in[35];

    float* ws   = (float*)d_ws;
    float* tblS = ws;                          // 32768
    float* xA   = tblS + 32768;                // 196608 (t1 ping)
    float* xB   = xA + 196608;                 // 196608 (t1 pong)
    float* qkv  = xB + 196608;                 // 589824 (f32 QKV)
    float* pbuf = qkv + 589824;                // 786432 (split-K partials)
    float* x2A  = pbuf + 786432;               // 52224 (t2 ping)
    float* x2B  = x2A + 52224;                 // 52224 (t2 pong)
    unsigned short* xb0 = (unsigned short*)(x2B + 52224);    // 196608 shorts
    unsigned short* obb = xb0 + 196608;        // 196608 shorts
    unsigned short* hb  = obb + 196608;        // 1572864 shorts
    unsigned short* x2b = hb + 1572864;        // 52224 shorts
    unsigned short* wbf = x2b + 52224 + 16;    // 5441536 shorts (16B aligned)
    unsigned short* wb_t1_attn = wbf;
    unsigned short* wb_t1_ffn1 = wbf + 524288;
    unsigned short* wb_t1_ffn2 = wbf + 1572864;
    unsigned short* wb_t2_attn = wbf + 2621440;
    unsigned short* wb_t2_ffn1 = wbf + 3213312;
    unsigned short* wb_t2_ffn2 = wbf + 4327424;
    int* ctr = (int*)(wbf + 5441536);          // work-queue counter

    auto gemm_f32 = [&](const unsigned short* A, const unsigned short* Wb, const float* bias,
                        float* Cc, int R, int Kk, int N) {
        dim3 g((N + 63) / 64, R / 64, 1);
        gemm_mfma_k<<<g, 256, 0, stream>>>(A, Wb, bias, Cc, (unsigned short*)0,
                                           R, Kk, N, 0, Kk, 0);
    };
    // split-K partials only (no epilogue) — consumed by a prologue or redln
    auto gemm_part = [&](const unsigned short* A, const unsigned short* Wb,
                         int R, int Kk, int N, int ns) {
        int ksl = ((Kk + ns - 1) / ns + 31) / 32 * 32;
        dim3 gr((N + 63) / 64, R / 64, ns);
        gemm_mfma_k<<<gr, 256, 0, stream>>>(A, Wb, (const float*)0, pbuf,
                                            (unsigned short*)0, R, Kk, N, 0, ksl, 0);
    };
    // GEMM with LN-prologue (A = LN(xres + bias_p + partials)), direct out
    auto gemm_pro = [&](int ns, const float* xres, const float* bias_p,
                        const float* lng, const float* lnb, float* x_out,
                        const unsigned short* Wb, const float* bias,
                        float* Cf, unsigned short* Cb,
                        int R, int Kk, int N, int relu, int obf) {
        dim3 g((N + 63) / 64, R / 64, 1);
        gemm_pro_k<<<g, 256, 0, stream>>>(pbuf, ns, xres, bias_p, lng, lnb, x_out,
                                          Wb, bias, Cf, Cb, R, Kk, N, relu, obf);
    };

    hipMemsetAsync(ctr, 0, sizeof(int), stream);
    scale_table_k<<<128, 256, 0, stream>>>(char_table, tblS);
    attvec_k<<<512, 1024, 0, stream>>>(chars, att_type, kw_idx, tblS,
                                       filter_w, filter_b, gate_w, gate_b,
                                       mlp_w, mlp_b, kw_table, aline_w, aline_b,
                                       xA, xb0, ctr,
                                       t1_attn_w, t1_ffn_w1, t1_ffn_w2,
                                       t2_attn_w, t2_ffn_w1, t2_ffn_w2, wbf);

    // ---- transformer 1: seq=12, batch=64, d=256 (x ping-pong xA/xB) ----
    {
        const unsigned short* awb0 = wb_t1_attn;
        const unsigned short* awb1 = wb_t1_attn + (size_t)4 * C_ * C_;
        const float* ab0 = t1_attn_b;
        const float* ab1 = t1_attn_b + 4 * C_;
        // L0
        gemm_f32(xb0, awb0, ab0, qkv, 768, C_, 3 * C_);
        attn_k<<<64, 256, 0, stream>>>(qkv, obb, 12, 64, C_, 0.0625f);
        gemm_part(obb, awb0 + 3 * C_ * C_, 768, C_, C_, 2);
        gemm_pro(2, xA, ab0 + 3 * C_, t1_ln_g, t1_ln_b, xB,
                 wb_t1_ffn1, t1_ffn_b1, (float*)0, hb, 768, C_, FF_, 1, 1);
        gemm_part(hb, wb_t1_ffn2, 768, FF_, C_, 4);
        // L1 (qkv consumes L0's ffn2 LN via prologue)
        gemm_pro(4, xB, t1_ffn_b2, t1_ln_g + C_, t1_ln_b + C_, xA,
                 awb1, ab1, qkv, (unsigned short*)0, 768, C_, 3 * C_, 0, 0);
        attn_k<<<64, 256, 0, stream>>>(qkv, obb, 12, 64, C_, 0.0625f);
        gemm_part(obb, awb1 + 3 * C_ * C_, 768, C_, C_, 2);
        gemm_pro(2, xA, ab1 + 3 * C_, t1_ln_g + 2 * C_, t1_ln_b + 2 * C_, xB,
                 wb_t1_ffn1 + (size_t)FF_ * C_, t1_ffn_b1 + FF_, (float*)0, hb,
                 768, C_, FF_, 1, 1);
        gemm_part(hb, wb_t1_ffn2 + (size_t)C_ * FF_, 768, FF_, C_, 4);
        // final LN of t1 -> xB in place (xb0 reused as scratch bf16)
        redln_k<<<768, 256, 0, stream>>>(pbuf, t1_ffn_b2 + C_, xB, xb0,
                                         t1_ln_g + 3 * C_, t1_ln_b + 3 * C_,
                                         C_, 4, 768 * C_);
    }

    build_x2_k<<<192, 256, 0, stream>>>(xB, stat, x2A, x2b);

    // ---- transformer 2: seq=8, batch=24, d=272 (ping-pong x2A/x2B) ----
    float sc2 = 1.0f / sqrtf(272.0f);
    {
        const unsigned short* awb0 = wb_t2_attn;
        const unsigned short* awb1 = wb_t2_attn + (size_t)4 * D2_ * D2_;
        const float* ab0 = t2_attn_b;
        const float* ab1 = t2_attn_b + 4 * D2_;
        // L0
        gemm_f32(x2b, awb0, ab0, qkv, 192, D2_, 3 * D2_);
        attn_k<<<24, 256, 0, stream>>>(qkv, obb, 8, 24, D2_, sc2);
        gemm_part(obb, awb0 + 3 * D2_ * D2_, 192, D2_, D2_, 4);
        gemm_pro(4, x2A, ab0 + 3 * D2_, t2_ln_g, t2_ln_b, x2B,
                 wb_t2_ffn1, t2_ffn_b1, (float*)0, hb, 192, D2_, FF_, 1, 1);
        gemm_part(hb, wb_t2_ffn2, 192, FF_, D2_, 8);
        // L1
        gemm_pro(8, x2B, t2_ffn_b2, t2_ln_g + D2_, t2_ln_b + D2_, x2A,
                 awb1, ab1, qkv, (unsigned short*)0, 192, D2_, 3 * D2_, 0, 0);
        attn_k<<<24, 256, 0, stream>>>(qkv, obb, 8, 24, D2_, sc2);
        gemm_part(obb, awb1 + 3 * D2_ * D2_, 192, D2_, D2_, 4);
        gemm_pro(4, x2A, ab1 + 3 * D2_, t2_ln_g + 2 * D2_, t2_ln_b + 2 * D2_, x2B,
                 wb_t2_ffn1 + (size_t)FF_ * D2_, t2_ffn_b1 + FF_, (float*)0, hb,
                 192, D2_, FF_, 1, 1);
        gemm_part(hb, wb_t2_ffn2 + (size_t)D2_ * FF_, 192, FF_, D2_, 8);
        redln_k<<<192, 256, 0, stream>>>(pbuf, t2_ffn_b2 + D2_, x2B, x2b,
                                         t2_ln_g + 3 * D2_, t2_ln_b + 3 * D2_,
                                         D2_, 8, 192 * D2_);
    }

    regressor_k<<<8, 256, 0, stream>>>(x2B, input_idx, kw_table, other,
                                       reg_w1, reg_b1, reg_w2, reg_b2, (float*)d_out);
}

// Round 14
// 319.517 us; speedup vs baseline: 2.7811x; 2.7811x over previous
//
#include <hip/hip_runtime.h>
#include <math.h>

// ---------------- constants ----------------
#define S_ 2
#define B_ 8
#define N_ 12
#define A_ 4
#define L_ 24
#define C_ 256
#define AUX_ 16
#define EK_ 64
#define K_ 256
#define M_ 8
#define OTH_ 32
#define D2_ 272
#define FF_ 2048
#define RIN_ 736
#define NSTR_ (S_*B_*N_*A_)   // 768
#define NCVT_ 256             // cvt chunks in the work queue
#define T4_ (5441536/4)       // 1360384 float4 chunks of weight data
#define CSZ_ (T4_/NCVT_)      // 5314 float4 per chunk (exact)

typedef __attribute__((ext_vector_type(8))) short short8v;   // bf16x8 MFMA frag
typedef __attribute__((ext_vector_type(4))) float f32x4;     // MFMA acc

__device__ __forceinline__ unsigned short f2bf(float f) {     // RNE f32->bf16
    unsigned u = __float_as_uint(f);
    return (unsigned short)((u + 0x7FFFu + ((u >> 16) & 1u)) >> 16);
}

// ---------------- K0: renorm char table (max_norm=1) ----------------
__global__ void scale_table_k(const float* __restrict__ tbl, float* __restrict__ out) {
    int r = blockIdx.x;          // 128 rows
    int c = threadIdx.x;         // 256
    float v = tbl[r * C_ + c];
    float sq = v * v;
    for (int off = 32; off; off >>= 1) sq += __shfl_down(sq, off);
    __shared__ float red[4];
    __shared__ float scl;
    if ((c & 63) == 0) red[c >> 6] = sq;
    __syncthreads();
    if (c == 0) {
        float n = sqrtf(red[0] + red[1] + red[2] + red[3]);
        scl = fminf(1.f, 1.f / fmaxf(n, 1e-7f));
    }
    __syncthreads();
    out[r * C_ + c] = v * scl;
}

// ---- K1: work-queue kernel: 768 strings + 256 weight-cvt chunks -----------
__global__ void attvec_k(const int* __restrict__ chars, const int* __restrict__ att_type,
                         const int* __restrict__ kw_idx, const float* __restrict__ tblS,
                         const float* __restrict__ fw, const float* __restrict__ fb,
                         const float* __restrict__ gw, const float* __restrict__ gb,
                         const float* __restrict__ mw, const float* __restrict__ mb,
                         const float* __restrict__ kwt, const float* __restrict__ aw,
                         const float* __restrict__ ab, float* __restrict__ x1,
                         unsigned short* __restrict__ x1b, int* __restrict__ ctr,
                         const float* __restrict__ s0, const float* __restrict__ s1,
                         const float* __restrict__ s2, const float* __restrict__ s3,
                         const float* __restrict__ s4, const float* __restrict__ s5,
                         unsigned short* __restrict__ wdst) {
    int tid = threadIdx.x;       // 0..1023
    int grp = tid >> 8;          // 0..3
    int c = tid & 255;
    __shared__ int su;
    __shared__ int ch[L_];
    __shared__ float xv[L_ + 2][C_];
    __shared__ float part[4][C_];

    const float L2E = 1.44269504f;
    float f0[4], f1[4], f2[4], fbv[4], g0[4], g1[4], g2[4], gbv[4], mwv[4];
    #pragma unroll
    for (int oo = 0; oo < 4; ++oo) {
        int o = grp * 4 + oo;
        f0[oo] = 2.f*L2E*fw[o*3]; f1[oo] = 2.f*L2E*fw[o*3+1]; f2[oo] = 2.f*L2E*fw[o*3+2];
        fbv[oo] = 2.f*L2E*fb[o];
        g0[oo] = L2E*gw[o*3]; g1[oo] = L2E*gw[o*3+1]; g2[oo] = L2E*gw[o*3+2];
        gbv[oo] = L2E*gb[o];
        mwv[oo] = mw[o];
    }

    for (;;) {
        __syncthreads();
        if (tid == 0) su = atomicAdd(ctr, 1);
        __syncthreads();
        int item = su;
        if (item >= NSTR_ + NCVT_) break;

        if (item >= NSTR_) {                     // ---- weight-cvt chunk ----
            int base = (item - NSTR_) * CSZ_;
            #pragma unroll
            for (int i = 0; i < 6; ++i) {
                int q = base + i * 1024 + tid;
                if (q < base + CSZ_) {
                    int idx = q * 4;
                    const float* src; int off;
                    if      (idx < 524288)  { src = s0; off = 0; }
                    else if (idx < 1572864) { src = s1; off = 524288; }
                    else if (idx < 2621440) { src = s2; off = 1572864; }
                    else if (idx < 3213312) { src = s3; off = 2621440; }
                    else if (idx < 4327424) { src = s4; off = 3213312; }
                    else                    { src = s5; off = 4327424; }
                    float4 v = *(const float4*)(src + (idx - off));
                    ushort4 o;
                    o.x = f2bf(v.x); o.y = f2bf(v.y); o.z = f2bf(v.z); o.w = f2bf(v.w);
                    *(ushort4*)(wdst + idx) = o;
                }
            }
            continue;
        }

        int str = item;
        bool kw = (att_type[str] == 1);
        float partial;
        if (kw) {
            const float* kr = kwt + kw_idx[str] * EK_ + grp * 16;
            const float* awr = aw + c * EK_ + grp * 16;
            float acc = (grp == 0) ? ab[c] : 0.f;
            #pragma unroll
            for (int e = 0; e < 16; ++e) acc = fmaf(kr[e], awr[e], acc);
            partial = acc;
        } else {
            if (tid < L_) ch[tid] = chars[str * L_ + tid];
            __syncthreads();
            #pragma unroll
            for (int i = 0; i < 6; ++i) {
                int l = grp * 6 + i;
                xv[l + 1][c] = tblS[ch[l] * C_ + c];
            }
            if (grp == 0) xv[0][c] = 0.f;
            if (grp == 3) xv[L_ + 1][c] = 0.f;
            __syncthreads();

            float osum[4] = {0.f, 0.f, 0.f, 0.f};
            float xm = xv[0][c], x0 = xv[1][c];
            for (int l = 1; l <= L_; ++l) {
                float xp = xv[l + 1][c];
                #pragma unroll
                for (int oo = 0; oo < 4; ++oo) {
                    float pf2 = fbv[oo] + f0[oo]*xm + f1[oo]*x0 + f2[oo]*xp;
                    float pg  = gbv[oo] + g0[oo]*xm + g1[oo]*x0 + g2[oo]*xp;
                    pf2 = fminf(fmaxf(pf2, -43.f), 43.f);
                    pg  = fminf(fmaxf(pg,  -22.f), 22.f);
                    float e1 = __builtin_amdgcn_exp2f(pf2);
                    float e2 = __builtin_amdgcn_exp2f(pg);
                    float num = (e1 - 1.f) * e2;
                    float den = (e1 + 1.f) * (e2 + 1.f);
                    osum[oo] = fmaf(num, __builtin_amdgcn_rcpf(den), osum[oo]);
                }
                xm = x0; x0 = xp;
            }
            partial = mwv[0]*osum[0] + mwv[1]*osum[1] + mwv[2]*osum[2] + mwv[3]*osum[3];
        }
        part[grp][c] = partial;
        __syncthreads();
        if (grp == 0) {
            int a = str & 3;
            int n = (str >> 2) % N_;
            int sb = str / (N_ * A_);
            int row = n * 64 + sb * 4 + a;
            float tot = part[0][c] + part[1][c] + part[2][c] + part[3][c];
            float out = kw ? tot : (mb[0] + tot * (1.f / 24.f));
            x1[row * C_ + c] = out;
            x1b[row * C_ + c] = f2bf(out);
        }
    }
}

// ---------------- MFMA GEMM, 2-deep register prefetch ----------------------
// gridDim.z == 1: direct out (f32 or bf16 via obf, +bias+relu).
// gridDim.z > 1 : f32 partials to Cf + z*R*N, no bias (reduced by redln_k).
// R9/R12/R13 lessons: no cross-block fences, no latency-chained prologues.
__global__ void gemm_mfma_k(const unsigned short* __restrict__ Ab,
                            const unsigned short* __restrict__ Wb,
                            const float* __restrict__ bias,
                            float* __restrict__ Cf, unsigned short* __restrict__ Cb,
                            int R, int K, int N, int relu, int kslice, int obf) {
    int tid = threadIdx.x;
    int wave = tid >> 6, lane = tid & 63;
    int fr = lane & 15, fq = lane >> 4;
    int m0 = blockIdx.y * 64;
    int n0 = blockIdx.x * 64 + wave * 16;
    int kbeg = blockIdx.z * kslice;
    int kend = min(kbeg + kslice, K);
    int col = n0 + fr;
    bool bok = col < N;
    const unsigned short* Wrow = Wb + (size_t)col * K;
    const unsigned short* Ar0 = Ab + (size_t)(m0 + fr) * K;
    const unsigned short* Ar1 = Ab + (size_t)(m0 + 16 + fr) * K;
    const unsigned short* Ar2 = Ab + (size_t)(m0 + 32 + fr) * K;
    const unsigned short* Ar3 = Ab + (size_t)(m0 + 48 + fr) * K;

    f32x4 acc0 = {0.f,0.f,0.f,0.f}, acc1 = {0.f,0.f,0.f,0.f};
    f32x4 acc2 = {0.f,0.f,0.f,0.f}, acc3 = {0.f,0.f,0.f,0.f};
    const short8v z8 = {0,0,0,0,0,0,0,0};
    short8v pb0, pa00, pa01, pa02, pa03;
    short8v pb1, pa10, pa11, pa12, pa13;

#define LDSET(PB,PA0,PA1,PA2,PA3,ktv) do {                                \
        int kl2 = (ktv) + fq * 8;                                         \
        bool kv2 = (kl2 + 8 <= kend);                                     \
        PB  = (bok && kv2) ? *(const short8v*)(Wrow + kl2) : z8;          \
        PA0 = kv2 ? *(const short8v*)(Ar0 + kl2) : z8;                    \
        PA1 = kv2 ? *(const short8v*)(Ar1 + kl2) : z8;                    \
        PA2 = kv2 ? *(const short8v*)(Ar2 + kl2) : z8;                    \
        PA3 = kv2 ? *(const short8v*)(Ar3 + kl2) : z8;                    \
    } while (0)

    if (kbeg < kend) {
        LDSET(pb0, pa00, pa01, pa02, pa03, kbeg);
        LDSET(pb1, pa10, pa11, pa12, pa13, kbeg + 32);
        for (int kt = kbeg; kt < kend; kt += 64) {
            short8v tb = pb0, t0 = pa00, t1 = pa01, t2 = pa02, t3 = pa03;
            LDSET(pb0, pa00, pa01, pa02, pa03, kt + 64);
            acc0 = __builtin_amdgcn_mfma_f32_16x16x32_bf16(t0, tb, acc0, 0, 0, 0);
            acc1 = __builtin_amdgcn_mfma_f32_16x16x32_bf16(t1, tb, acc1, 0, 0, 0);
            acc2 = __builtin_amdgcn_mfma_f32_16x16x32_bf16(t2, tb, acc2, 0, 0, 0);
            acc3 = __builtin_amdgcn_mfma_f32_16x16x32_bf16(t3, tb, acc3, 0, 0, 0);
            short8v ub = pb1, u0 = pa10, u1 = pa11, u2 = pa12, u3 = pa13;
            LDSET(pb1, pa10, pa11, pa12, pa13, kt + 96);
            acc0 = __builtin_amdgcn_mfma_f32_16x16x32_bf16(u0, ub, acc0, 0, 0, 0);
            acc1 = __builtin_amdgcn_mfma_f32_16x16x32_bf16(u1, ub, acc1, 0, 0, 0);
            acc2 = __builtin_amdgcn_mfma_f32_16x16x32_bf16(u2, ub, acc2, 0, 0, 0);
            acc3 = __builtin_amdgcn_mfma_f32_16x16x32_bf16(u3, ub, acc3, 0, 0, 0);
        }
    }
#undef LDSET

    if (!bok) return;
    bool direct = (gridDim.z == 1);
    float bv = direct ? bias[col] : 0.f;
    float* outf = direct ? Cf : (Cf + (size_t)blockIdx.z * R * N);
#define STOREACC(accv, mi) do {                                           \
        _Pragma("unroll")                                                 \
        for (int j = 0; j < 4; ++j) {                                     \
            int row = m0 + (mi)*16 + fq * 4 + j;                          \
            float v = accv[j] + bv;                                       \
            if (direct && relu) v = fmaxf(v, 0.f);                        \
            if (direct && obf) Cb[(size_t)row * N + col] = f2bf(v);       \
            else               outf[(size_t)row * N + col] = v;           \
        }                                                                 \
    } while (0)
    STOREACC(acc0, 0); STOREACC(acc1, 1); STOREACC(acc2, 2); STOREACC(acc3, 3);
#undef STOREACC
}

// ------- fused split-K reduce + bias + residual + LayerNorm (f32 + bf16) ---
__global__ void redln_k(const float* __restrict__ part, const float* __restrict__ bias,
                        float* __restrict__ x, unsigned short* __restrict__ xb,
                        const float* __restrict__ g, const float* __restrict__ b,
                        int d, int NS, int RN) {
    int r = blockIdx.x, tid = threadIdx.x;
    __shared__ float red[10];
    const float* xr = x + (size_t)r * d;
    int i0 = tid, i1 = tid + 256;
    bool h0 = i0 < d, h1 = i1 < d;
    float v0 = 0.f, v1 = 0.f;
    if (h0) {
        v0 = xr[i0] + bias[i0];
        for (int z = 0; z < NS; ++z) v0 += part[(size_t)z * RN + (size_t)r * d + i0];
    }
    if (h1) {
        v1 = xr[i1] + bias[i1];
        for (int z = 0; z < NS; ++z) v1 += part[(size_t)z * RN + (size_t)r * d + i1];
    }
    float s = v0 + v1, ss = v0 * v0 + v1 * v1;
    for (int off = 32; off; off >>= 1) {
        s += __shfl_down(s, off);
        ss += __shfl_down(ss, off);
    }
    if ((tid & 63) == 0) { red[(tid >> 6) * 2] = s; red[(tid >> 6) * 2 + 1] = ss; }
    __syncthreads();
    if (tid == 0) {
        float S = red[0] + red[2] + red[4] + red[6];
        float SS = red[1] + red[3] + red[5] + red[7];
        float mu = S / d;
        float var = SS / d - mu * mu;
        red[8] = mu;
        red[9] = rsqrtf(var + 1e-5f);
    }
    __syncthreads();
    float mu = red[8], inv = red[9];
    float* xw = x + (size_t)r * d;
    if (h0) {
        float o = (v0 - mu) * inv * g[i0] + b[i0];
        xw[i0] = o; xb[(size_t)r * d + i0] = f2bf(o);
    }
    if (h1) {
        float o = (v1 - mu) * inv * g[i1] + b[i1];
        xw[i1] = o; xb[(size_t)r * d + i1] = f2bf(o);
    }
}

// ---------------- attention: 4-lane score dot, padded LDS ------------------
__global__ void attn_k(const float* __restrict__ qkv, unsigned short* __restrict__ ob,
                       int seq, int batch, int d, float scale) {
    __shared__ float sm[3 * 12 * 260];
    __shared__ float sc[12 * 12];
    int j = blockIdx.x, tid = threadIdx.x;
    int dp = d + 4;
    int s3 = 3 * d;
    float* qs = sm;
    float* ks = sm + 12 * 260;
    float* vs = sm + 2 * 12 * 260;
    for (int idx = tid; idx < seq * d; idx += 256) {
        int s = idx / d, cc = idx - s * d;
        const float* base = qkv + (size_t)(s * batch + j) * s3 + cc;
        qs[s * dp + cc] = base[0];
        ks[s * dp + cc] = base[d];
        vs[s * dp + cc] = base[2 * d];
    }
    __syncthreads();
    for (int p4 = tid; p4 < seq * seq * 4; p4 += 256) {
        int p = p4 >> 2, sub = p4 & 3;
        int s = p / seq, t = p - s * seq;
        const float* qp = qs + s * dp;
        const float* kp = ks + t * dp;
        float acc = 0.f;
        for (int cc = sub; cc < d; cc += 4) acc = fmaf(qp[cc], kp[cc], acc);
        acc += __shfl_xor(acc, 1);
        acc += __shfl_xor(acc, 2);
        if (sub == 0) sc[p] = acc * scale;
    }
    __syncthreads();
    if (tid < seq) {
        float m = -1e30f;
        for (int t = 0; t < seq; ++t) m = fmaxf(m, sc[tid * seq + t]);
        float ssum = 0.f;
        for (int t = 0; t < seq; ++t) {
            float e = __expf(sc[tid * seq + t] - m);
            sc[tid * seq + t] = e;
            ssum += e;
        }
        float inv = 1.f / ssum;
        for (int t = 0; t < seq; ++t) sc[tid * seq + t] *= inv;
    }
    __syncthreads();
    for (int c = tid; c < d; c += 256) {
        for (int s = 0; s < seq; ++s) {
            float acc = 0.f;
            for (int t = 0; t < seq; ++t) acc = fmaf(sc[s * seq + t], vs[t * dp + c], acc);
            ob[(size_t)(s * batch + j) * d + c] = f2bf(acc);
        }
    }
}

// ---------------- build x2: mean over attrs + concat static ----------------
__global__ void build_x2_k(const float* __restrict__ y1, const float* __restrict__ stat,
                           float* __restrict__ x2, unsigned short* __restrict__ x2b) {
    int id = blockIdx.x;                 // 192 blocks
    int n = id % N_;
    int b = (id / N_) % B_;
    int s = id / (N_ * B_);
    int orow = b * (S_ * N_) + s * N_ + n;
    for (int c = threadIdx.x; c < D2_; c += 256) {
        float v;
        if (c < C_) {
            int j0 = (s * B_ + b) * A_;
            float acc = 0.f;
            for (int a = 0; a < A_; ++a) acc += y1[(size_t)(n * 64 + j0 + a) * C_ + c];
            v = acc * 0.25f;
        } else {
            v = stat[((size_t)(s * B_ + b) * N_ + n) * AUX_ + (c - C_)];
        }
        x2[(size_t)orow * D2_ + c] = v;
        x2b[(size_t)orow * D2_ + c] = f2bf(v);
    }
}

// ------- regressor (fused node-mean): build real + feats + 2-layer MLP -----
__global__ void regressor_k(const float* __restrict__ y2, const int* __restrict__ input_idx,
                            const float* __restrict__ kwt, const float* __restrict__ other,
                            const float* __restrict__ w1, const float* __restrict__ b1,
                            const float* __restrict__ w2, const float* __restrict__ b2,
                            float* __restrict__ out) {
    int b = blockIdx.x;                  // 8
    int tid = threadIdx.x;               // 256
    __shared__ float realsh[2][D2_];
    __shared__ float feats[RIN_];
    __shared__ float hh[32];
    for (int idx = tid; idx < 2 * D2_; idx += 256) {
        int s = idx / D2_, c = idx - s * D2_;
        float acc = 0.f;
        for (int n = 0; n < N_; ++n)
            acc += y2[(size_t)(b * 24 + s * N_ + n) * D2_ + c];
        realsh[s][c] = acc * (1.f / 12.f);
    }
    __syncthreads();
    for (int i = tid; i < RIN_; i += 256) {
        float v;
        if (i < 64) {
            float acc = 0.f;
            for (int m = 0; m < M_; ++m) acc += kwt[input_idx[b * M_ + m] * EK_ + i];
            v = acc * 0.125f;
        } else if (i < 336) {
            v = realsh[0][i - 64];
        } else if (i < 400) {
            int e = i - 336;
            float acc = 0.f;
            for (int m = 0; m < M_; ++m) acc += kwt[input_idx[64 + b * M_ + m] * EK_ + e];
            v = acc * 0.125f;
        } else if (i < 672) {
            v = realsh[1][i - 400];
        } else {
            v = other[b * 64 + (i - 672)];
        }
        feats[i] = v;
    }
    __syncthreads();
    if (tid < 32) {
        float acc = b1[tid];
        const float* wr = w1 + (size_t)tid * RIN_;
        for (int i = 0; i < RIN_; ++i) acc += feats[i] * wr[i];
        hh[tid] = fmaxf(acc, 0.f);
    }
    __syncthreads();
    if (tid == 0) {
        float acc = b2[0];
        for (int j = 0; j < 32; ++j) acc += hh[j] * w2[j];
        out[b] = acc;
    }
}

// ---------------- host ----------------
extern "C" void kernel_launch(void* const* d_in, const int* in_sizes, int n_in,
                              void* d_out, int out_size, void* d_ws, size_t ws_size,
                              hipStream_t stream) {
    const int*   chars      = (const int*)d_in[0];
    const int*   att_type   = (const int*)d_in[1];
    const int*   kw_idx     = (const int*)d_in[2];
    const int*   input_idx  = (const int*)d_in[3];
    const float* stat       = (const float*)d_in[4];
    const float* other      = (const float*)d_in[5];
    const float* char_table = (const float*)d_in[6];
    const float* filter_w   = (const float*)d_in[7];
    const float* filter_b   = (const float*)d_in[8];
    const float* gate_w     = (const float*)d_in[9];
    const float* gate_b     = (const float*)d_in[10];
    const float* mlp_w      = (const float*)d_in[11];
    const float* mlp_b      = (const float*)d_in[12];
    const float* kw_table   = (const float*)d_in[13];
    const float* aline_w    = (const float*)d_in[14];
    const float* aline_b    = (const float*)d_in[15];
    const float* t1_attn_w  = (const float*)d_in[16];
    const float* t1_attn_b  = (const float*)d_in[17];
    const float* t1_ffn_w1  = (const float*)d_in[18];
    const float* t1_ffn_b1  = (const float*)d_in[19];
    const float* t1_ffn_w2  = (const float*)d_in[20];
    const float* t1_ffn_b2  = (const float*)d_in[21];
    const float* t1_ln_g    = (const float*)d_in[22];
    const float* t1_ln_b    = (const float*)d_in[23];
    const float* t2_attn_w  = (const float*)d_in[24];
    const float* t2_attn_b  = (const float*)d_in[25];
    const float* t2_ffn_w1  = (const float*)d_in[26];
    const float* t2_ffn_b1  = (const float*)d_in[27];
    const float* t2_ffn_w2  = (const float*)d_in[28];
    const float* t2_ffn_b2  = (const float*)d_in[29];
    const float* t2_ln_g    = (const float*)d_in[30];
    const float* t2_ln_b    = (const float*)d_in[31];
    const float* reg_w1     = (const float*)d_in[32];
    const float* reg_b1     = (const float*)d_in[33];
    const float* reg_w2     = (const float*)d_in[34];
    const float* reg_b2     = (const float*)d_in[35];

    float* ws   = (float*)d_ws;
    float* tblS = ws;                          // 32768
    float* x1   = tblS + 32768;                // 196608
    float* qkv  = x1 + 196608;                 // 589824 (f32 QKV)
    float* pbuf = qkv + 589824;                // 786432 (split-K partials)
    float* x2   = pbuf + 786432;               // 52224
    float* spare= x2 + 52224;                  // 4352 (layout stability)
    unsigned short* x1b = (unsigned short*)(spare + 4352);   // 196608 shorts
    unsigned short* obb = x1b + 196608;        // 196608 shorts
    unsigned short* hb  = obb + 196608;        // 1572864 shorts
    unsigned short* x2b = hb + 1572864;        // 52224 shorts
    unsigned short* wbf = x2b + 52224 + 16;    // 5441536 shorts (16B aligned)
    unsigned short* wb_t1_attn = wbf;
    unsigned short* wb_t1_ffn1 = wbf + 524288;
    unsigned short* wb_t1_ffn2 = wbf + 1572864;
    unsigned short* wb_t2_attn = wbf + 2621440;
    unsigned short* wb_t2_ffn1 = wbf + 3213312;
    unsigned short* wb_t2_ffn2 = wbf + 4327424;
    int* ctr = (int*)(wbf + 5441536);          // work-queue counter

    auto gemm_f32 = [&](const unsigned short* A, const unsigned short* Wb, const float* bias,
                        float* Cc, int R, int Kk, int N) {
        dim3 g((N + 63) / 64, R / 64, 1);
        gemm_mfma_k<<<g, 256, 0, stream>>>(A, Wb, bias, Cc, (unsigned short*)0,
                                           R, Kk, N, 0, Kk, 0);
    };
    auto gemm_bf16 = [&](const unsigned short* A, const unsigned short* Wb, const float* bias,
                         unsigned short* Cc, int R, int Kk, int N) {
        dim3 g((N + 63) / 64, R / 64, 1);
        gemm_mfma_k<<<g, 256, 0, stream>>>(A, Wb, bias, (float*)0, Cc,
                                           R, Kk, N, 1, Kk, 1);
    };
    // split-K GEMM + separate fused reduce+bias+residual+LN dispatch
    auto gemm_split_ln = [&](const unsigned short* A, const unsigned short* Wb,
                             const float* bias, float* x, unsigned short* xb,
                             const float* g, const float* b,
                             int R, int Kk, int N, int ns) {
        int ksl = ((Kk + ns - 1) / ns + 31) / 32 * 32;
        dim3 gr((N + 63) / 64, R / 64, ns);
        gemm_mfma_k<<<gr, 256, 0, stream>>>(A, Wb, bias, pbuf, (unsigned short*)0,
                                            R, Kk, N, 0, ksl, 0);
        redln_k<<<R, 256, 0, stream>>>(pbuf, bias, x, xb, g, b, N, ns, R * N);
    };

    hipMemsetAsync(ctr, 0, sizeof(int), stream);
    scale_table_k<<<128, 256, 0, stream>>>(char_table, tblS);
    attvec_k<<<512, 1024, 0, stream>>>(chars, att_type, kw_idx, tblS,
                                       filter_w, filter_b, gate_w, gate_b,
                                       mlp_w, mlp_b, kw_table, aline_w, aline_b,
                                       x1, x1b, ctr,
                                       t1_attn_w, t1_ffn_w1, t1_ffn_w2,
                                       t2_attn_w, t2_ffn_w1, t2_ffn_w2, wbf);

    // ---- transformer 1: seq=12, batch=64, d=256 ----
    for (int i = 0; i < 2; ++i) {
        const unsigned short* awb = wb_t1_attn + (size_t)i * 4 * C_ * C_;
        const float* ab = t1_attn_b + (size_t)i * 4 * C_;
        gemm_f32(x1b, awb, ab, qkv, 768, C_, 3 * C_);
        attn_k<<<64, 256, 0, stream>>>(qkv, obb, 12, 64, C_, 0.0625f);
        gemm_split_ln(obb, awb + 3 * C_ * C_, ab + 3 * C_, x1, x1b,
                      t1_ln_g + i * 2 * C_, t1_ln_b + i * 2 * C_, 768, C_, C_, 4);
        gemm_bf16(x1b, wb_t1_ffn1 + (size_t)i * FF_ * C_, t1_ffn_b1 + i * FF_, hb, 768, C_, FF_);
        gemm_split_ln(hb, wb_t1_ffn2 + (size_t)i * C_ * FF_, t1_ffn_b2 + i * C_, x1, x1b,
                      t1_ln_g + i * 2 * C_ + C_, t1_ln_b + i * 2 * C_ + C_, 768, FF_, C_, 4);
    }

    build_x2_k<<<192, 256, 0, stream>>>(x1, stat, x2, x2b);

    // ---- transformer 2: seq=8, batch=24, d=272 ----
    float sc2 = 1.0f / sqrtf(272.0f);
    for (int i = 0; i < 2; ++i) {
        const unsigned short* awb = wb_t2_attn + (size_t)i * 4 * D2_ * D2_;
        const float* ab = t2_attn_b + (size_t)i * 4 * D2_;
        gemm_f32(x2b, awb, ab, qkv, 192, D2_, 3 * D2_);
        attn_k<<<24, 256, 0, stream>>>(qkv, obb, 8, 24, D2_, sc2);
        gemm_split_ln(obb, awb + 3 * D2_ * D2_, ab + 3 * D2_, x2, x2b,
                      t2_ln_g + i * 2 * D2_, t2_ln_b + i * 2 * D2_, 192, D2_, D2_, 4);
        gemm_bf16(x2b, wb_t2_ffn1 + (size_t)i * FF_ * D2_, t2_ffn_b1 + i * FF_, hb, 192, D2_, FF_);
        gemm_split_ln(hb, wb_t2_ffn2 + (size_t)i * D2_ * FF_, t2_ffn_b2 + i * D2_, x2, x2b,
                      t2_ln_g + i * 2 * D2_ + D2_, t2_ln_b + i * 2 * D2_ + D2_, 192, FF_, D2_, 8);
    }

    regressor_k<<<8, 256, 0, stream>>>(x2, input_idx, kw_table, other,
                                       reg_w1, reg_b1, reg_w2, reg_b2, (float*)d_out);
}